// Round 8
// baseline (206.852 us; speedup 1.0000x reference)
//
#include <hip/hip_runtime.h>
#include <hip/hip_bf16.h>
#include <math.h>

#define BB 2
#define SS 4096
#define HH 16
#define DD 128
#define CK 64
#define NTC 64
#define HD 2048          // H*D row stride (elements)
#define SQ 136           // LDS row stride (shorts), rows of 128 (q, k)
#define ST 72            // LDS row stride (shorts), rows of 64 (kT, vT)

typedef __attribute__((ext_vector_type(8))) short bh8;     // 8 bf16
typedef __attribute__((ext_vector_type(16))) float fx16;   // 32x32 accumulator

#define MFMA32(a, b, c) __builtin_amdgcn_mfma_f32_32x32x16_bf16(a, b, c, 0, 0, 0)
// short-offset XOR swizzle: spreads the 8-row bank period across 4 16B slots
#define SWZ(off, row) ((off) ^ (8 * (((row) >> 3) & 3)))

__device__ inline unsigned pk2(float a, float b) {   // 2xf32 -> packed bf16 (RNE, hw cvt)
    union { __hip_bfloat162 h2; unsigned u; } r;
    r.h2.x = __float2bfloat16(a);
    r.h2.y = __float2bfloat16(b);
    return r.u;
}
// packed bf16 -> 2xf32 (exact); macro so it can assign to vector elements
#define UPK(u, x, y) { x = __uint_as_float((unsigned)(u) << 16); y = __uint_as_float((unsigned)(u) & 0xFFFF0000u); }

// exchange: x' = {x.lo, y.lo(partner)}, y' = {x.hi(partner), y.hi}
#define SWAP32(x, y) asm("v_permlane32_swap_b32 %0, %1" : "+v"(x), "+v"(y))

// Build an MFMA A/B fragment (8 consecutive k per hi-half) from 16 C/D-layout
// f32 regs: pack pairs, one permlane swap fixes the hi-half mismatch.
#define MKFRAG(dst, cc, O) { \
    unsigned a0_ = pk2(cc[(O)+0], cc[(O)+1]), a1_ = pk2(cc[(O)+2], cc[(O)+3]); \
    unsigned a2_ = pk2(cc[(O)+4], cc[(O)+5]), a3_ = pk2(cc[(O)+6], cc[(O)+7]); \
    SWAP32(a0_, a2_); SWAP32(a1_, a3_); \
    union { unsigned u[4]; bh8 v; } r_; \
    r_.u[0] = a0_; r_.u[1] = a1_; r_.u[2] = a2_; r_.u[3] = a3_; \
    dst = r_.v; }

// ---------------- Phase 1: per-group K^T V sums (dbuf, reg-h, bf16 frag G) ----------
// At its HBM floor (~20us = 128MB cold k,v read). (512,2): r6 showed (512,4) -> spill.
__global__ __launch_bounds__(512, 2) void ksum_kernel(const float* __restrict__ k,
                                                      const float* __restrict__ v,
                                                      unsigned* __restrict__ G,
                                                      int CPG, int NG) {
    int g = blockIdx.x, h = blockIdx.y, b = blockIdx.z;
    int t = threadIdx.x, l = t & 63, w = t >> 6, hi = l >> 5, lm = l & 31;
    int dbp = 2 * (w >> 2), eb = w & 3;   // wave owns h tiles (dbp,eb),(dbp+1,eb)
    __shared__ short lkT[2][128 * ST];
    __shared__ short lvT[2][128 * ST];
    fx16 h0 = {}, h1 = {};
    long hbase = ((long)b * SS) * HD + (long)h * DD;
    float kt[16], vt[16];

#define KLOAD(cc) { long base_ = hbase + (long)(g * CPG + (cc)) * CK * HD; \
    _Pragma("unroll") for (int i = 0; i < 8; ++i) { int it = t + 512 * i; \
        int e = (it & 31) + 32 * (it >> 10); int c2 = (it >> 5) & 31; \
        long ga = base_ + (long)(2 * c2) * HD + e; \
        kt[2*i] = k[ga]; kt[2*i+1] = k[ga + HD]; \
        vt[2*i] = v[ga]; vt[2*i+1] = v[ga + HD]; } }

#define KSTAGE(pn) { \
    _Pragma("unroll") for (int i = 0; i < 8; ++i) { int it = t + 512 * i; \
        int e = (it & 31) + 32 * (it >> 10); int c2 = (it >> 5) & 31; \
        *(unsigned*)&lkT[pn][e * ST + SWZ(2 * c2, e)] = pk2(kt[2*i], kt[2*i+1]); \
        *(unsigned*)&lvT[pn][e * ST + SWZ(2 * c2, e)] = pk2(vt[2*i], vt[2*i+1]); } }

    KLOAD(0); KSTAGE(0); if (CPG > 1) KLOAD(1);
    __syncthreads();
    int p = 0;
    for (int c = 0; c < CPG; ++c) {
        if (c + 1 < CPG) KSTAGE(p ^ 1);
        if (c + 2 < CPG) KLOAD(c + 2);
        bh8 Bv0 = *(const bh8*)&lvT[p][(32*eb+lm)*ST + SWZ( 0 + 8*hi, lm)];
        bh8 Bv1 = *(const bh8*)&lvT[p][(32*eb+lm)*ST + SWZ(16 + 8*hi, lm)];
        bh8 Bv2 = *(const bh8*)&lvT[p][(32*eb+lm)*ST + SWZ(32 + 8*hi, lm)];
        bh8 Bv3 = *(const bh8*)&lvT[p][(32*eb+lm)*ST + SWZ(48 + 8*hi, lm)];
        __builtin_amdgcn_s_setprio(1);
#define KM4(hx, db) { \
        bh8 A0_ = *(const bh8*)&lkT[p][(32*(db)+lm)*ST + SWZ( 0 + 8*hi, lm)]; hx = MFMA32(A0_, Bv0, hx); \
        bh8 A1_ = *(const bh8*)&lkT[p][(32*(db)+lm)*ST + SWZ(16 + 8*hi, lm)]; hx = MFMA32(A1_, Bv1, hx); \
        bh8 A2_ = *(const bh8*)&lkT[p][(32*(db)+lm)*ST + SWZ(32 + 8*hi, lm)]; hx = MFMA32(A2_, Bv2, hx); \
        bh8 A3_ = *(const bh8*)&lkT[p][(32*(db)+lm)*ST + SWZ(48 + 8*hi, lm)]; hx = MFMA32(A3_, Bv3, hx); }
        KM4(h0, dbp) KM4(h1, dbp + 1)
        __builtin_amdgcn_s_setprio(0);
        __syncthreads();
        p ^= 1;
    }
    // bf16 fragment-ordered G: tile (db,eb) at (db*4+eb)*512 u32 + lane*8
    unsigned* Gp = G + ((long)(b * HH + h) * NG + g) * (DD * DD / 2);
    long t0 = (long)(dbp * 4 + eb) * 512 + l * 8;
    long t1 = (long)((dbp + 1) * 4 + eb) * 512 + l * 8;
    uint4 u;
    u.x = pk2(h0[0],h0[1]);  u.y = pk2(h0[2],h0[3]);  u.z = pk2(h0[4],h0[5]);  u.w = pk2(h0[6],h0[7]);
    *(uint4*)(Gp + t0) = u;
    u.x = pk2(h0[8],h0[9]);  u.y = pk2(h0[10],h0[11]); u.z = pk2(h0[12],h0[13]); u.w = pk2(h0[14],h0[15]);
    *(uint4*)(Gp + t0 + 4) = u;
    u.x = pk2(h1[0],h1[1]);  u.y = pk2(h1[2],h1[3]);  u.z = pk2(h1[4],h1[5]);  u.w = pk2(h1[6],h1[7]);
    *(uint4*)(Gp + t1) = u;
    u.x = pk2(h1[8],h1[9]);  u.y = pk2(h1[10],h1[11]); u.z = pk2(h1[12],h1[13]); u.w = pk2(h1[14],h1[15]);
    *(uint4*)(Gp + t1 + 4) = u;
}

// ---------------- Phase 2: exclusive prefix over groups (in-place, bf16 frags) -------
__global__ __launch_bounds__(256) void prefix_kernel(unsigned* __restrict__ G,
                                                     float* __restrict__ hf,
                                                     int NG) {
    int tid = blockIdx.x * 256 + threadIdx.x;     // 65536 threads
    int bh = tid >> 11;
    int fl = (tid & 2047) * 8;                    // frag float base within bh
    unsigned* Gb = G + (long)bh * NG * (DD * DD / 2) + fl / 2;
    float a[8] = {0.f, 0.f, 0.f, 0.f, 0.f, 0.f, 0.f, 0.f};
    uint4 nxt = *(uint4*)Gb;
    for (int g = 0; g < NG; ++g) {
        uint4 cur = nxt;
        if (g + 1 < NG) nxt = *(uint4*)(Gb + (long)(g + 1) * (DD * DD / 2));
        uint4 st;
        st.x = pk2(a[0], a[1]); st.y = pk2(a[2], a[3]);
        st.z = pk2(a[4], a[5]); st.w = pk2(a[6], a[7]);
        *(uint4*)(Gb + (long)g * (DD * DD / 2)) = st;
        float x, y;
        UPK(cur.x, x, y); a[0] += x; a[1] += y;
        UPK(cur.y, x, y); a[2] += x; a[3] += y;
        UPK(cur.z, x, y); a[4] += x; a[5] += y;
        UPK(cur.w, x, y); a[6] += x; a[7] += y;
    }
    // scatter running total into semantic final_state hf[d][e] (f32)
    float* hb = hf + (long)bh * (DD * DD);
    int tile = fl >> 10, li = (fl >> 4) & 63;
#pragma unroll
    for (int j = 0; j < 8; ++j) {
        int rg = (fl & 15) + j;
        int d = 32 * (tile >> 2) + (rg & 3) + 8 * (rg >> 2) + 4 * (li >> 5);
        int e = 32 * (tile & 3) + (li & 31);
        hb[d * DD + e] = a[j];
    }
}

// ---------------- Phase 3: scan, 256-thr blocks (4 waves), 2 blocks/CU TLP ----------
// Wave w owns e-slice w of h (4 d-tiles, 64 regs, NO duplication) and of o (64x32).
__global__ __launch_bounds__(256, 2) void scan_kernel(const float* __restrict__ q,
                                                      const float* __restrict__ kk,
                                                      const float* __restrict__ vv,
                                                      const unsigned* __restrict__ G,
                                                      float* __restrict__ o,
                                                      int CPG, int NG, float scale) {
    int g = blockIdx.x, h = blockIdx.y, b = blockIdx.z;
    int t = threadIdx.x, l = t & 63, w = t >> 6, hi = l >> 5, lm = l & 31;
    int eb = w;                       // e-slice 0..3
    __shared__ short lq [64 * SQ];
    __shared__ short lk [64 * SQ];
    __shared__ short lkT[128 * ST];
    __shared__ short lvT[128 * ST];

    // h state: 4 d-tiles of e-slice eb, C/D layout, f32 regs
    fx16 h0 = {}, h1 = {}, h2 = {}, h3 = {};
    {
        const unsigned* Gp = G + ((long)(b * HH + h) * NG + g) * (DD * DD / 2);
#define GINIT(hx, db) { const unsigned* p_ = Gp + (long)((db) * 4 + eb) * 512 + l * 8; \
        uint4 u0 = *(const uint4*)p_; uint4 u1 = *(const uint4*)(p_ + 4); \
        UPK(u0.x, hx[0], hx[1]);  UPK(u0.y, hx[2], hx[3]); \
        UPK(u0.z, hx[4], hx[5]);  UPK(u0.w, hx[6], hx[7]); \
        UPK(u1.x, hx[8], hx[9]);  UPK(u1.y, hx[10], hx[11]); \
        UPK(u1.z, hx[12], hx[13]); UPK(u1.w, hx[14], hx[15]); }
        GINIT(h0, 0) GINIT(h1, 1) GINIT(h2, 2) GINIT(h3, 3)
    }

    long hbase = ((long)b * SS) * HD + (long)h * DD;
    int r4 = t >> 2, c4 = t & 3;      // staging: 4 threads per row

    for (int c = 0; c < CPG; ++c) {
        long base = hbase + (long)(g * CPG + c) * CK * HD;
        // ---- stage q,k row-major (other resident block computes meanwhile) ----
#pragma unroll
        for (int j = 0; j < 8; ++j) {
            long ga = base + (long)r4 * HD + 4 * (c4 + 4 * j);
            float4 qv = *(const float4*)&q[ga];
            float4 kv = *(const float4*)&kk[ga];
            uint2 uq; uq.x = pk2(qv.x * scale, qv.y * scale); uq.y = pk2(qv.z * scale, qv.w * scale);
            *(uint2*)&lq[r4 * SQ + SWZ(4 * (c4 + 4 * j), r4)] = uq;
            uint2 uk; uk.x = pk2(kv.x, kv.y); uk.y = pk2(kv.z, kv.w);
            *(uint2*)&lk[r4 * SQ + SWZ(4 * (c4 + 4 * j), r4)] = uk;
        }
        // ---- stage kT,vT (transposed global reads, coalesced 128B segments) ----
#pragma unroll
        for (int i = 0; i < 16; ++i) {
            int it = t + 256 * i;                       // 0..4095
            int e = (it & 31) + 32 * (it >> 10);
            int c2 = (it >> 5) & 31;
            long ga = base + (long)(2 * c2) * HD + e;
            *(unsigned*)&lkT[e * ST + SWZ(2 * c2, e)] = pk2(kk[ga], kk[ga + HD]);
            *(unsigned*)&lvT[e * ST + SWZ(2 * c2, e)] = pk2(vv[ga], vv[ga + HD]);
        }
        __syncthreads();   // stage visible

        __builtin_amdgcn_s_setprio(1);
        // ---- m1: S^T tiles (c-tile, r-tile) = (0,0),(0,1),(1,1); (1,0) is zero ----
        fx16 st00 = {}, st01 = {}, st11 = {};
#pragma unroll
        for (int ks = 0; ks < 8; ++ks) {
            bh8 ak0 = *(const bh8*)&lk[lm * SQ        + SWZ(16*ks + 8*hi, lm)];
            bh8 ak1 = *(const bh8*)&lk[(32+lm) * SQ   + SWZ(16*ks + 8*hi, lm)];
            bh8 qf0 = *(const bh8*)&lq[lm * SQ        + SWZ(16*ks + 8*hi, lm)];
            bh8 qf1 = *(const bh8*)&lq[(32+lm) * SQ   + SWZ(16*ks + 8*hi, lm)];
            st00 = MFMA32(ak0, qf0, st00);
            st01 = MFMA32(ak0, qf1, st01);
            st11 = MFMA32(ak1, qf1, st11);
        }

        // shared B-operands from vT (e-slice eb) for m2/m4
        bh8 Bv0 = *(const bh8*)&lvT[(32*eb+lm)*ST + SWZ( 0 + 8*hi, lm)];
        bh8 Bv1 = *(const bh8*)&lvT[(32*eb+lm)*ST + SWZ(16 + 8*hi, lm)];
        bh8 Bv2 = *(const bh8*)&lvT[(32*eb+lm)*ST + SWZ(32 + 8*hi, lm)];
        bh8 Bv3 = *(const bh8*)&lvT[(32*eb+lm)*ST + SWZ(48 + 8*hi, lm)];

        // ---- m2: o = S @ v (A-frags from reg S^T via MKFRAG; diag tiles masked) ----
        fx16 oa0 = {}, oa1 = {};
        {
            float ms[16];
#pragma unroll
            for (int rg = 0; rg < 16; ++rg) {           // mask st00: keep c <= r
                int cc_ = (rg & 3) + 8 * (rg >> 2) + 4 * hi;
                ms[rg] = (cc_ <= lm) ? st00[rg] : 0.f;
            }
            bh8 f0, f1; MKFRAG(f0, ms, 0) MKFRAG(f1, ms, 8)
            oa0 = MFMA32(f0, Bv0, oa0);
            oa0 = MFMA32(f1, Bv1, oa0);
        }
        {
            bh8 f0, f1; MKFRAG(f0, st01, 0) MKFRAG(f1, st01, 8)
            oa1 = MFMA32(f0, Bv0, oa1);
            oa1 = MFMA32(f1, Bv1, oa1);
            float ms[16];
#pragma unroll
            for (int rg = 0; rg < 16; ++rg) {           // mask st11 (same local test)
                int cc_ = (rg & 3) + 8 * (rg >> 2) + 4 * hi;
                ms[rg] = (cc_ <= lm) ? st11[rg] : 0.f;
            }
            bh8 f2, f3; MKFRAG(f2, ms, 0) MKFRAG(f3, ms, 8)
            oa1 = MFMA32(f2, Bv2, oa1);
            oa1 = MFMA32(f3, Bv3, oa1);
        }
        // ---- m3: o += qs @ h (B-frags from reg h; Bh shared across both r-tiles) ----
#define M3STEP(hx, db) { \
        bh8 Bh0; MKFRAG(Bh0, hx, 0); \
        bh8 Aq0 = *(const bh8*)&lq[lm * SQ      + SWZ(16*(2*(db)) + 8*hi, lm)]; \
        bh8 Aq1 = *(const bh8*)&lq[(32+lm) * SQ + SWZ(16*(2*(db)) + 8*hi, lm)]; \
        oa0 = MFMA32(Aq0, Bh0, oa0); oa1 = MFMA32(Aq1, Bh0, oa1); \
        bh8 Bh1; MKFRAG(Bh1, hx, 8); \
        bh8 Aq2 = *(const bh8*)&lq[lm * SQ      + SWZ(16*(2*(db)+1) + 8*hi, lm)]; \
        bh8 Aq3 = *(const bh8*)&lq[(32+lm) * SQ + SWZ(16*(2*(db)+1) + 8*hi, lm)]; \
        oa0 = MFMA32(Aq2, Bh1, oa0); oa1 = MFMA32(Aq3, Bh1, oa1); }
        M3STEP(h0, 0) M3STEP(h1, 1) M3STEP(h2, 2) M3STEP(h3, 3)

        // ---- m4: h += k^T v ----
#define M4STEP(hx, db) { \
        bh8 A0_ = *(const bh8*)&lkT[(32*(db)+lm)*ST + SWZ( 0 + 8*hi, lm)]; hx = MFMA32(A0_, Bv0, hx); \
        bh8 A1_ = *(const bh8*)&lkT[(32*(db)+lm)*ST + SWZ(16 + 8*hi, lm)]; hx = MFMA32(A1_, Bv1, hx); \
        bh8 A2_ = *(const bh8*)&lkT[(32*(db)+lm)*ST + SWZ(32 + 8*hi, lm)]; hx = MFMA32(A2_, Bv2, hx); \
        bh8 A3_ = *(const bh8*)&lkT[(32*(db)+lm)*ST + SWZ(48 + 8*hi, lm)]; hx = MFMA32(A3_, Bv3, hx); }
        M4STEP(h0, 0) M4STEP(h1, 1) M4STEP(h2, 2) M4STEP(h3, 3)
        __builtin_amdgcn_s_setprio(0);

        // ---- o write: oa0 rows 0-31, oa1 rows 32-63, col 32*eb+lm ----
        {
            float* op = o + base;
            int e = 32 * eb + lm;
#pragma unroll
            for (int rg = 0; rg < 16; ++rg) {
                int r = (rg & 3) + 8 * (rg >> 2) + 4 * hi;
                op[(long)r * HD + e]        = oa0[rg];
                op[(long)(32 + r) * HD + e] = oa1[rg];
            }
        }
        __syncthreads();   // all reads done before next stage overwrites
    }
}

extern "C" void kernel_launch(void* const* d_in, const int* in_sizes, int n_in,
                              void* d_out, int out_size, void* d_ws, size_t ws_size,
                              hipStream_t stream) {
    const float* q = (const float*)d_in[0];
    const float* k = (const float*)d_in[1];
    const float* v = (const float*)d_in[2];
    float* o  = (float*)d_out;
    float* hf = o + (long)BB * SS * HH * DD;
    unsigned* G = (unsigned*)d_ws;

    int NG = 16;
    while (NG > 1 && (size_t)BB * HH * NG * DD * DD * 2 > ws_size) NG >>= 1;
    int CPG = NTC / NG;
    float scale = 1.0f / sqrtf((float)DD);

    ksum_kernel<<<dim3(NG, HH, BB), 512, 0, stream>>>(k, v, G, CPG, NG);
    prefix_kernel<<<dim3(256, 1, 1), 256, 0, stream>>>(G, hf, NG);
    scan_kernel<<<dim3(NG, HH, BB), 256, 0, stream>>>(q, k, v, G, o, CPG, NG, scale);
}

// Round 9
// 195.090 us; speedup vs baseline: 1.0603x; 1.0603x over previous
//
#include <hip/hip_runtime.h>
#include <hip/hip_bf16.h>
#include <math.h>

#define BB 2
#define SS 4096
#define HH 16
#define DD 128
#define CK 64
#define NTC 64
#define HD 2048          // H*D row stride (elements)
#define SQ 136           // LDS row stride (shorts), rows of 128 (q, k)
#define ST 72            // LDS row stride (shorts), rows of 64 (kT, vT, S)

typedef __attribute__((ext_vector_type(8))) short bh8;     // 8 bf16
typedef __attribute__((ext_vector_type(16))) float fx16;   // 32x32 accumulator

#define MFMA32(a, b, c) __builtin_amdgcn_mfma_f32_32x32x16_bf16(a, b, c, 0, 0, 0)
// short-offset XOR swizzle: spreads the 8-row bank period across 4 16B slots
#define SWZ(off, row) ((off) ^ (8 * (((row) >> 3) & 3)))

__device__ inline unsigned pk2(float a, float b) {   // 2xf32 -> packed bf16 (RNE, hw cvt)
    union { __hip_bfloat162 h2; unsigned u; } r;
    r.h2.x = __float2bfloat16(a);
    r.h2.y = __float2bfloat16(b);
    return r.u;
}
// packed bf16 -> 2xf32 (exact); macro so it can assign to vector elements
#define UPK(u, x, y) { x = __uint_as_float((unsigned)(u) << 16); y = __uint_as_float((unsigned)(u) & 0xFFFF0000u); }

// exchange: x' = {x.lo, y.lo(partner)}, y' = {x.hi(partner), y.hi}
#define SWAP32(x, y) asm("v_permlane32_swap_b32 %0, %1" : "+v"(x), "+v"(y))

// Build an MFMA A/B fragment (8 consecutive k per hi-half) from 16 C/D-layout
// f32 regs: pack pairs, one permlane swap fixes the hi-half mismatch.
#define MKFRAG(dst, cc, O) { \
    unsigned a0_ = pk2(cc[(O)+0], cc[(O)+1]), a1_ = pk2(cc[(O)+2], cc[(O)+3]); \
    unsigned a2_ = pk2(cc[(O)+4], cc[(O)+5]), a3_ = pk2(cc[(O)+6], cc[(O)+7]); \
    SWAP32(a0_, a2_); SWAP32(a1_, a3_); \
    union { unsigned u[4]; bh8 v; } r_; \
    r_.u[0] = a0_; r_.u[1] = a1_; r_.u[2] = a2_; r_.u[3] = a3_; \
    dst = r_.v; }

// ---------------- Phase 1: per-group K^T V sums (dbuf, reg-h, bf16 frag G) ----------
// At its HBM floor (~20us = 128MB cold k,v read).
__global__ __launch_bounds__(512, 2) void ksum_kernel(const float* __restrict__ k,
                                                      const float* __restrict__ v,
                                                      unsigned* __restrict__ G,
                                                      int CPG, int NG) {
    int g = blockIdx.x, h = blockIdx.y, b = blockIdx.z;
    int t = threadIdx.x, l = t & 63, w = t >> 6, hi = l >> 5, lm = l & 31;
    int dbp = 2 * (w >> 2), eb = w & 3;   // wave owns h tiles (dbp,eb),(dbp+1,eb)
    __shared__ short lkT[2][128 * ST];
    __shared__ short lvT[2][128 * ST];
    fx16 h0 = {}, h1 = {};
    long hbase = ((long)b * SS) * HD + (long)h * DD;
    float kt[16], vt[16];

#define KLOAD(cc) { long base_ = hbase + (long)(g * CPG + (cc)) * CK * HD; \
    _Pragma("unroll") for (int i = 0; i < 8; ++i) { int it = t + 512 * i; \
        int e = (it & 31) + 32 * (it >> 10); int c2 = (it >> 5) & 31; \
        long ga = base_ + (long)(2 * c2) * HD + e; \
        kt[2*i] = k[ga]; kt[2*i+1] = k[ga + HD]; \
        vt[2*i] = v[ga]; vt[2*i+1] = v[ga + HD]; } }

#define KSTAGE(pn) { \
    _Pragma("unroll") for (int i = 0; i < 8; ++i) { int it = t + 512 * i; \
        int e = (it & 31) + 32 * (it >> 10); int c2 = (it >> 5) & 31; \
        *(unsigned*)&lkT[pn][e * ST + SWZ(2 * c2, e)] = pk2(kt[2*i], kt[2*i+1]); \
        *(unsigned*)&lvT[pn][e * ST + SWZ(2 * c2, e)] = pk2(vt[2*i], vt[2*i+1]); } }

    KLOAD(0); KSTAGE(0); if (CPG > 1) KLOAD(1);
    __syncthreads();
    int p = 0;
    for (int c = 0; c < CPG; ++c) {
        if (c + 1 < CPG) KSTAGE(p ^ 1);
        if (c + 2 < CPG) KLOAD(c + 2);
        bh8 Bv0 = *(const bh8*)&lvT[p][(32*eb+lm)*ST + SWZ( 0 + 8*hi, lm)];
        bh8 Bv1 = *(const bh8*)&lvT[p][(32*eb+lm)*ST + SWZ(16 + 8*hi, lm)];
        bh8 Bv2 = *(const bh8*)&lvT[p][(32*eb+lm)*ST + SWZ(32 + 8*hi, lm)];
        bh8 Bv3 = *(const bh8*)&lvT[p][(32*eb+lm)*ST + SWZ(48 + 8*hi, lm)];
        __builtin_amdgcn_s_setprio(1);
#define KM4(hx, db) { \
        bh8 A0_ = *(const bh8*)&lkT[p][(32*(db)+lm)*ST + SWZ( 0 + 8*hi, lm)]; hx = MFMA32(A0_, Bv0, hx); \
        bh8 A1_ = *(const bh8*)&lkT[p][(32*(db)+lm)*ST + SWZ(16 + 8*hi, lm)]; hx = MFMA32(A1_, Bv1, hx); \
        bh8 A2_ = *(const bh8*)&lkT[p][(32*(db)+lm)*ST + SWZ(32 + 8*hi, lm)]; hx = MFMA32(A2_, Bv2, hx); \
        bh8 A3_ = *(const bh8*)&lkT[p][(32*(db)+lm)*ST + SWZ(48 + 8*hi, lm)]; hx = MFMA32(A3_, Bv3, hx); }
        KM4(h0, dbp) KM4(h1, dbp + 1)
        __builtin_amdgcn_s_setprio(0);
        __syncthreads();
        p ^= 1;
    }
    // bf16 fragment-ordered G: tile (db,eb) at (db*4+eb)*512 u32 + lane*8
    unsigned* Gp = G + ((long)(b * HH + h) * NG + g) * (DD * DD / 2);
    long t0 = (long)(dbp * 4 + eb) * 512 + l * 8;
    long t1 = (long)((dbp + 1) * 4 + eb) * 512 + l * 8;
    uint4 u;
    u.x = pk2(h0[0],h0[1]);  u.y = pk2(h0[2],h0[3]);  u.z = pk2(h0[4],h0[5]);  u.w = pk2(h0[6],h0[7]);
    *(uint4*)(Gp + t0) = u;
    u.x = pk2(h0[8],h0[9]);  u.y = pk2(h0[10],h0[11]); u.z = pk2(h0[12],h0[13]); u.w = pk2(h0[14],h0[15]);
    *(uint4*)(Gp + t0 + 4) = u;
    u.x = pk2(h1[0],h1[1]);  u.y = pk2(h1[2],h1[3]);  u.z = pk2(h1[4],h1[5]);  u.w = pk2(h1[6],h1[7]);
    *(uint4*)(Gp + t1) = u;
    u.x = pk2(h1[8],h1[9]);  u.y = pk2(h1[10],h1[11]); u.z = pk2(h1[12],h1[13]); u.w = pk2(h1[14],h1[15]);
    *(uint4*)(Gp + t1 + 4) = u;
}

// ---------------- Phase 2: exclusive prefix over groups (in-place, bf16 frags) -------
__global__ __launch_bounds__(256) void prefix_kernel(unsigned* __restrict__ G,
                                                     float* __restrict__ hf,
                                                     int NG) {
    int tid = blockIdx.x * 256 + threadIdx.x;     // 65536 threads
    int bh = tid >> 11;
    int fl = (tid & 2047) * 8;                    // frag float base within bh
    unsigned* Gb = G + (long)bh * NG * (DD * DD / 2) + fl / 2;
    float a[8] = {0.f, 0.f, 0.f, 0.f, 0.f, 0.f, 0.f, 0.f};
    uint4 nxt = *(uint4*)Gb;
    for (int g = 0; g < NG; ++g) {
        uint4 cur = nxt;
        if (g + 1 < NG) nxt = *(uint4*)(Gb + (long)(g + 1) * (DD * DD / 2));
        uint4 st;
        st.x = pk2(a[0], a[1]); st.y = pk2(a[2], a[3]);
        st.z = pk2(a[4], a[5]); st.w = pk2(a[6], a[7]);
        *(uint4*)(Gb + (long)g * (DD * DD / 2)) = st;
        float x, y;
        UPK(cur.x, x, y); a[0] += x; a[1] += y;
        UPK(cur.y, x, y); a[2] += x; a[3] += y;
        UPK(cur.z, x, y); a[4] += x; a[5] += y;
        UPK(cur.w, x, y); a[6] += x; a[7] += y;
    }
    // scatter running total into semantic final_state hf[d][e] (f32)
    float* hb = hf + (long)bh * (DD * DD);
    int tile = fl >> 10, li = (fl >> 4) & 63;
#pragma unroll
    for (int j = 0; j < 8; ++j) {
        int rg = (fl & 15) + j;
        int d = 32 * (tile >> 2) + (rg & 3) + 8 * (rg >> 2) + 4 * (li >> 5);
        int e = 32 * (tile & 3) + (li & 31);
        hb[d * DD + e] = a[j];
    }
}

// ---------------- Phase 3: scan, 256-thr, S shared via LDS, 2 blocks/CU, no spill ----
// Wave w owns e-slice w of h (64 acc regs) and o (64x32). Waves 0-2 compute the 3
// nonzero S^T tiles once per block into lS (masked, bf16). acc total ~112/wave.
__global__ __launch_bounds__(256, 2) void scan_kernel(const float* __restrict__ q,
                                                      const float* __restrict__ kk,
                                                      const float* __restrict__ vv,
                                                      const unsigned* __restrict__ G,
                                                      float* __restrict__ o,
                                                      int CPG, int NG, float scale) {
    int g = blockIdx.x, h = blockIdx.y, b = blockIdx.z;
    int t = threadIdx.x, l = t & 63, w = t >> 6, hi = l >> 5, lm = l & 31;
    int eb = w;                       // e-slice 0..3
    __shared__ short lq [64 * SQ];    // 17408 B
    __shared__ short lk [64 * SQ];    // 17408 B
    __shared__ short lkT[128 * ST];   // 18432 B
    __shared__ short lvT[128 * ST];   // 18432 B
    __shared__ short lS [64 * ST];    //  9216 B   (total 80896 <= 81920 for 2/CU)

    // h state: 4 d-tiles of e-slice eb, C/D layout, f32 regs
    fx16 h0 = {}, h1 = {}, h2 = {}, h3 = {};
    {
        const unsigned* Gp = G + ((long)(b * HH + h) * NG + g) * (DD * DD / 2);
#define GINIT(hx, db) { const unsigned* p_ = Gp + (long)((db) * 4 + eb) * 512 + l * 8; \
        uint4 u0 = *(const uint4*)p_; uint4 u1 = *(const uint4*)(p_ + 4); \
        UPK(u0.x, hx[0], hx[1]);  UPK(u0.y, hx[2], hx[3]); \
        UPK(u0.z, hx[4], hx[5]);  UPK(u0.w, hx[6], hx[7]); \
        UPK(u1.x, hx[8], hx[9]);  UPK(u1.y, hx[10], hx[11]); \
        UPK(u1.z, hx[12], hx[13]); UPK(u1.w, hx[14], hx[15]); }
        GINIT(h0, 0) GINIT(h1, 1) GINIT(h2, 2) GINIT(h3, 3)
    }

    long hbase = ((long)b * SS) * HD + (long)h * DD;
    int r4 = t >> 2, c4 = t & 3;      // staging: 4 threads per row

    for (int c = 0; c < CPG; ++c) {
        long base = hbase + (long)(g * CPG + c) * CK * HD;
        // ---- stage q,k row-major ----
#pragma unroll
        for (int j = 0; j < 8; ++j) {
            long ga = base + (long)r4 * HD + 4 * (c4 + 4 * j);
            float4 qv = *(const float4*)&q[ga];
            float4 kv = *(const float4*)&kk[ga];
            uint2 uq; uq.x = pk2(qv.x * scale, qv.y * scale); uq.y = pk2(qv.z * scale, qv.w * scale);
            *(uint2*)&lq[r4 * SQ + SWZ(4 * (c4 + 4 * j), r4)] = uq;
            uint2 uk; uk.x = pk2(kv.x, kv.y); uk.y = pk2(kv.z, kv.w);
            *(uint2*)&lk[r4 * SQ + SWZ(4 * (c4 + 4 * j), r4)] = uk;
        }
        // ---- stage kT,vT (transposed global reads, 128B segments) ----
#pragma unroll
        for (int i = 0; i < 16; ++i) {
            int it = t + 256 * i;                       // 0..4095
            int e = (it & 31) + 32 * (it >> 10);
            int c2 = (it >> 5) & 31;
            long ga = base + (long)(2 * c2) * HD + e;
            *(unsigned*)&lkT[e * ST + SWZ(2 * c2, e)] = pk2(kk[ga], kk[ga + HD]);
            *(unsigned*)&lvT[e * ST + SWZ(2 * c2, e)] = pk2(vv[ga], vv[ga + HD]);
        }
        __syncthreads();   // B1: stage visible

        __builtin_amdgcn_s_setprio(1);
        // ---- m1 (waves 0-2): one S^T tile each -> masked bf16 -> lS (S row-major) ----
        if (w < 3) {
            int ct = (w == 2) ? 1 : 0;      // c-tile
            int rt = (w == 0) ? 0 : 1;      // r-tile;  (ct,rt) in {(0,0),(0,1),(1,1)}
            fx16 st = {};
#pragma unroll
            for (int ks = 0; ks < 8; ++ks) {
                bh8 A = *(const bh8*)&lk[(32*ct+lm)*SQ + SWZ(16*ks + 8*hi, lm)];
                bh8 B = *(const bh8*)&lq[(32*rt+lm)*SQ + SWZ(16*ks + 8*hi, lm)];
                st = MFMA32(A, B, st);
            }
            bool diag = (ct == rt);
#pragma unroll
            for (int q4 = 0; q4 < 4; ++q4) {
                float m[4];
#pragma unroll
                for (int j = 0; j < 4; ++j) {
                    int cc_ = 8 * q4 + 4 * hi + j;     // local col within tile
                    float x = st[4 * q4 + j];
                    m[j] = (!diag || cc_ <= lm) ? x : 0.f;
                }
                uint2 u; u.x = pk2(m[0], m[1]); u.y = pk2(m[2], m[3]);
                *(uint2*)&lS[(32*rt+lm)*ST + SWZ(32*ct + 8*q4 + 4*hi, lm)] = u;
            }
        }
        __syncthreads();   // B2: S visible

        // shared B-operands from vT (e-slice eb) for m2/m4
        bh8 Bv0 = *(const bh8*)&lvT[(32*eb+lm)*ST + SWZ( 0 + 8*hi, lm)];
        bh8 Bv1 = *(const bh8*)&lvT[(32*eb+lm)*ST + SWZ(16 + 8*hi, lm)];
        bh8 Bv2 = *(const bh8*)&lvT[(32*eb+lm)*ST + SWZ(32 + 8*hi, lm)];
        bh8 Bv3 = *(const bh8*)&lvT[(32*eb+lm)*ST + SWZ(48 + 8*hi, lm)];

        // ---- m2: o = S @ v (A-frags straight from lS) ----
        fx16 oa0 = {}, oa1 = {};
        {
            bh8 A0 = *(const bh8*)&lS[lm*ST      + SWZ( 0 + 8*hi, lm)];
            bh8 A1 = *(const bh8*)&lS[lm*ST      + SWZ(16 + 8*hi, lm)];
            oa0 = MFMA32(A0, Bv0, oa0);
            oa0 = MFMA32(A1, Bv1, oa0);
            bh8 B0 = *(const bh8*)&lS[(32+lm)*ST + SWZ( 0 + 8*hi, lm)];
            bh8 B1 = *(const bh8*)&lS[(32+lm)*ST + SWZ(16 + 8*hi, lm)];
            bh8 B2 = *(const bh8*)&lS[(32+lm)*ST + SWZ(32 + 8*hi, lm)];
            bh8 B3 = *(const bh8*)&lS[(32+lm)*ST + SWZ(48 + 8*hi, lm)];
            oa1 = MFMA32(B0, Bv0, oa1);
            oa1 = MFMA32(B1, Bv1, oa1);
            oa1 = MFMA32(B2, Bv2, oa1);
            oa1 = MFMA32(B3, Bv3, oa1);
        }
        // ---- m3: o += qs @ h (B-frags from reg h; Bh shared across both r-tiles) ----
#define M3STEP(hx, db) { \
        bh8 Bh0; MKFRAG(Bh0, hx, 0); \
        bh8 Aq0 = *(const bh8*)&lq[lm * SQ      + SWZ(16*(2*(db)) + 8*hi, lm)]; \
        bh8 Aq1 = *(const bh8*)&lq[(32+lm) * SQ + SWZ(16*(2*(db)) + 8*hi, lm)]; \
        oa0 = MFMA32(Aq0, Bh0, oa0); oa1 = MFMA32(Aq1, Bh0, oa1); \
        bh8 Bh1; MKFRAG(Bh1, hx, 8); \
        bh8 Aq2 = *(const bh8*)&lq[lm * SQ      + SWZ(16*(2*(db)+1) + 8*hi, lm)]; \
        bh8 Aq3 = *(const bh8*)&lq[(32+lm) * SQ + SWZ(16*(2*(db)+1) + 8*hi, lm)]; \
        oa0 = MFMA32(Aq2, Bh1, oa0); oa1 = MFMA32(Aq3, Bh1, oa1); }
        M3STEP(h0, 0) M3STEP(h1, 1) M3STEP(h2, 2) M3STEP(h3, 3)

        // ---- m4: h += k^T v ----
#define M4STEP(hx, db) { \
        bh8 A0_ = *(const bh8*)&lkT[(32*(db)+lm)*ST + SWZ( 0 + 8*hi, lm)]; hx = MFMA32(A0_, Bv0, hx); \
        bh8 A1_ = *(const bh8*)&lkT[(32*(db)+lm)*ST + SWZ(16 + 8*hi, lm)]; hx = MFMA32(A1_, Bv1, hx); \
        bh8 A2_ = *(const bh8*)&lkT[(32*(db)+lm)*ST + SWZ(32 + 8*hi, lm)]; hx = MFMA32(A2_, Bv2, hx); \
        bh8 A3_ = *(const bh8*)&lkT[(32*(db)+lm)*ST + SWZ(48 + 8*hi, lm)]; hx = MFMA32(A3_, Bv3, hx); }
        M4STEP(h0, 0) M4STEP(h1, 1) M4STEP(h2, 2) M4STEP(h3, 3)
        __builtin_amdgcn_s_setprio(0);

        // ---- o write: oa0 rows 0-31, oa1 rows 32-63, col 32*eb+lm ----
        {
            float* op = o + base;
            int e = 32 * eb + lm;
#pragma unroll
            for (int rg = 0; rg < 16; ++rg) {
                int r = (rg & 3) + 8 * (rg >> 2) + 4 * hi;
                op[(long)r * HD + e]        = oa0[rg];
                op[(long)(32 + r) * HD + e] = oa1[rg];
            }
        }
        __syncthreads();   // B3: all reads done before next stage overwrites
    }
}

extern "C" void kernel_launch(void* const* d_in, const int* in_sizes, int n_in,
                              void* d_out, int out_size, void* d_ws, size_t ws_size,
                              hipStream_t stream) {
    const float* q = (const float*)d_in[0];
    const float* k = (const float*)d_in[1];
    const float* v = (const float*)d_in[2];
    float* o  = (float*)d_out;
    float* hf = o + (long)BB * SS * HH * DD;
    unsigned* G = (unsigned*)d_ws;

    int NG = 16;
    while (NG > 1 && (size_t)BB * HH * NG * DD * DD * 2 > ws_size) NG >>= 1;
    int CPG = NTC / NG;
    float scale = 1.0f / sqrtf((float)DD);

    ksum_kernel<<<dim3(NG, HH, BB), 512, 0, stream>>>(k, v, G, CPG, NG);
    prefix_kernel<<<dim3(256, 1, 1), 256, 0, stream>>>(G, hf, NG);
    scan_kernel<<<dim3(NG, HH, BB), 256, 0, stream>>>(q, k, v, G, o, CPG, NG, scale);
}

// Round 10
// 93.615 us; speedup vs baseline: 2.2096x; 2.0840x over previous
//
#include <hip/hip_runtime.h>
#include <hip/hip_bf16.h>
#include <math.h>

#define BB 2
#define SS 4096
#define HH 16
#define DD 128
#define CK 64
#define NTC 64
#define HD 2048          // H*D row stride (elements)
#define SQ 136           // LDS row stride (shorts), rows of 128 (q, k)
#define ST 72            // LDS row stride (shorts), rows of 64 (kT, vT, S)

typedef __attribute__((ext_vector_type(8))) short bh8;     // 8 bf16
typedef __attribute__((ext_vector_type(16))) float fx16;   // 32x32 accumulator

#define MFMA32(a, b, c) __builtin_amdgcn_mfma_f32_32x32x16_bf16(a, b, c, 0, 0, 0)
// short-offset XOR swizzle: spreads the 8-row bank period across 4 16B slots
#define SWZ(off, row) ((off) ^ (8 * (((row) >> 3) & 3)))

__device__ inline unsigned pk2(float a, float b) {   // 2xf32 -> packed bf16 (RNE, hw cvt)
    union { __hip_bfloat162 h2; unsigned u; } r;
    r.h2.x = __float2bfloat16(a);
    r.h2.y = __float2bfloat16(b);
    return r.u;
}
// packed bf16 -> 2xf32 (exact); macro so it can assign to vector elements
#define UPK(u, x, y) { x = __uint_as_float((unsigned)(u) << 16); y = __uint_as_float((unsigned)(u) & 0xFFFF0000u); }

// exchange: x' = {x.lo, y.lo(partner)}, y' = {x.hi(partner), y.hi}
#define SWAP32(x, y) asm("v_permlane32_swap_b32 %0, %1" : "+v"(x), "+v"(y))

// Build an MFMA A/B fragment (8 consecutive k per hi-half) from 16 C/D-layout
// f32 regs: pack pairs, one permlane swap fixes the hi-half mismatch.
#define MKFRAG(dst, cc, O) { \
    unsigned a0_ = pk2(cc[(O)+0], cc[(O)+1]), a1_ = pk2(cc[(O)+2], cc[(O)+3]); \
    unsigned a2_ = pk2(cc[(O)+4], cc[(O)+5]), a3_ = pk2(cc[(O)+6], cc[(O)+7]); \
    SWAP32(a0_, a2_); SWAP32(a1_, a3_); \
    union { unsigned u[4]; bh8 v; } r_; \
    r_.u[0] = a0_; r_.u[1] = a1_; r_.u[2] = a2_; r_.u[3] = a3_; \
    dst = r_.v; }

// ---------------- Phase 1: per-group K^T V sums (dbuf, reg-h, bf16 frag G) ----------
// At its HBM floor (~20us = 128MB cold k,v read).
__global__ __launch_bounds__(512, 2) void ksum_kernel(const float* __restrict__ k,
                                                      const float* __restrict__ v,
                                                      unsigned* __restrict__ G,
                                                      int CPG, int NG) {
    int g = blockIdx.x, h = blockIdx.y, b = blockIdx.z;
    int t = threadIdx.x, l = t & 63, w = t >> 6, hi = l >> 5, lm = l & 31;
    int dbp = 2 * (w >> 2), eb = w & 3;   // wave owns h tiles (dbp,eb),(dbp+1,eb)
    __shared__ short lkT[2][128 * ST];
    __shared__ short lvT[2][128 * ST];
    fx16 h0 = {}, h1 = {};
    long hbase = ((long)b * SS) * HD + (long)h * DD;
    float kt[16], vt[16];

#define KLOAD(cc) { long base_ = hbase + (long)(g * CPG + (cc)) * CK * HD; \
    _Pragma("unroll") for (int i = 0; i < 8; ++i) { int it = t + 512 * i; \
        int e = (it & 31) + 32 * (it >> 10); int c2 = (it >> 5) & 31; \
        long ga = base_ + (long)(2 * c2) * HD + e; \
        kt[2*i] = k[ga]; kt[2*i+1] = k[ga + HD]; \
        vt[2*i] = v[ga]; vt[2*i+1] = v[ga + HD]; } }

#define KSTAGE(pn) { \
    _Pragma("unroll") for (int i = 0; i < 8; ++i) { int it = t + 512 * i; \
        int e = (it & 31) + 32 * (it >> 10); int c2 = (it >> 5) & 31; \
        *(unsigned*)&lkT[pn][e * ST + SWZ(2 * c2, e)] = pk2(kt[2*i], kt[2*i+1]); \
        *(unsigned*)&lvT[pn][e * ST + SWZ(2 * c2, e)] = pk2(vt[2*i], vt[2*i+1]); } }

    KLOAD(0); KSTAGE(0); if (CPG > 1) KLOAD(1);
    __syncthreads();
    int p = 0;
    for (int c = 0; c < CPG; ++c) {
        if (c + 1 < CPG) KSTAGE(p ^ 1);
        if (c + 2 < CPG) KLOAD(c + 2);
        bh8 Bv0 = *(const bh8*)&lvT[p][(32*eb+lm)*ST + SWZ( 0 + 8*hi, lm)];
        bh8 Bv1 = *(const bh8*)&lvT[p][(32*eb+lm)*ST + SWZ(16 + 8*hi, lm)];
        bh8 Bv2 = *(const bh8*)&lvT[p][(32*eb+lm)*ST + SWZ(32 + 8*hi, lm)];
        bh8 Bv3 = *(const bh8*)&lvT[p][(32*eb+lm)*ST + SWZ(48 + 8*hi, lm)];
        __builtin_amdgcn_s_setprio(1);
#define KM4(hx, db) { \
        bh8 A0_ = *(const bh8*)&lkT[p][(32*(db)+lm)*ST + SWZ( 0 + 8*hi, lm)]; hx = MFMA32(A0_, Bv0, hx); \
        bh8 A1_ = *(const bh8*)&lkT[p][(32*(db)+lm)*ST + SWZ(16 + 8*hi, lm)]; hx = MFMA32(A1_, Bv1, hx); \
        bh8 A2_ = *(const bh8*)&lkT[p][(32*(db)+lm)*ST + SWZ(32 + 8*hi, lm)]; hx = MFMA32(A2_, Bv2, hx); \
        bh8 A3_ = *(const bh8*)&lkT[p][(32*(db)+lm)*ST + SWZ(48 + 8*hi, lm)]; hx = MFMA32(A3_, Bv3, hx); }
        KM4(h0, dbp) KM4(h1, dbp + 1)
        __builtin_amdgcn_s_setprio(0);
        __syncthreads();
        p ^= 1;
    }
    // bf16 fragment-ordered G: tile (db,eb) at (db*4+eb)*512 u32 + lane*8
    unsigned* Gp = G + ((long)(b * HH + h) * NG + g) * (DD * DD / 2);
    long t0 = (long)(dbp * 4 + eb) * 512 + l * 8;
    long t1 = (long)((dbp + 1) * 4 + eb) * 512 + l * 8;
    uint4 u;
    u.x = pk2(h0[0],h0[1]);  u.y = pk2(h0[2],h0[3]);  u.z = pk2(h0[4],h0[5]);  u.w = pk2(h0[6],h0[7]);
    *(uint4*)(Gp + t0) = u;
    u.x = pk2(h0[8],h0[9]);  u.y = pk2(h0[10],h0[11]); u.z = pk2(h0[12],h0[13]); u.w = pk2(h0[14],h0[15]);
    *(uint4*)(Gp + t0 + 4) = u;
    u.x = pk2(h1[0],h1[1]);  u.y = pk2(h1[2],h1[3]);  u.z = pk2(h1[4],h1[5]);  u.w = pk2(h1[6],h1[7]);
    *(uint4*)(Gp + t1) = u;
    u.x = pk2(h1[8],h1[9]);  u.y = pk2(h1[10],h1[11]); u.z = pk2(h1[12],h1[13]); u.w = pk2(h1[14],h1[15]);
    *(uint4*)(Gp + t1 + 4) = u;
}

// ---------------- Phase 2: exclusive prefix over groups (in-place, bf16 frags) -------
__global__ __launch_bounds__(256) void prefix_kernel(unsigned* __restrict__ G,
                                                     float* __restrict__ hf,
                                                     int NG) {
    int tid = blockIdx.x * 256 + threadIdx.x;     // 65536 threads
    int bh = tid >> 11;
    int fl = (tid & 2047) * 8;                    // frag float base within bh
    unsigned* Gb = G + (long)bh * NG * (DD * DD / 2) + fl / 2;
    float a[8] = {0.f, 0.f, 0.f, 0.f, 0.f, 0.f, 0.f, 0.f};
    uint4 nxt = *(uint4*)Gb;
    for (int g = 0; g < NG; ++g) {
        uint4 cur = nxt;
        if (g + 1 < NG) nxt = *(uint4*)(Gb + (long)(g + 1) * (DD * DD / 2));
        uint4 st;
        st.x = pk2(a[0], a[1]); st.y = pk2(a[2], a[3]);
        st.z = pk2(a[4], a[5]); st.w = pk2(a[6], a[7]);
        *(uint4*)(Gb + (long)g * (DD * DD / 2)) = st;
        float x, y;
        UPK(cur.x, x, y); a[0] += x; a[1] += y;
        UPK(cur.y, x, y); a[2] += x; a[3] += y;
        UPK(cur.z, x, y); a[4] += x; a[5] += y;
        UPK(cur.w, x, y); a[6] += x; a[7] += y;
    }
    // scatter running total into semantic final_state hf[d][e] (f32)
    float* hb = hf + (long)bh * (DD * DD);
    int tile = fl >> 10, li = (fl >> 4) & 63;
#pragma unroll
    for (int j = 0; j < 8; ++j) {
        int rg = (fl & 15) + j;
        int d = 32 * (tile >> 2) + (rg & 3) + 8 * (rg >> 2) + 4 * (li >> 5);
        int e = 32 * (tile & 3) + (li & 31);
        hb[d * DD + e] = a[j];
    }
}

// ---------------- Phase 3: scan, 256-thr, S via LDS, capped staging unroll ----------
// Wave w owns e-slice w of h (64 acc regs) and o (64x32). Staging unroll capped at
// 2/4 to keep arch-VGPR <= 128 (r8/r9: unroll 8/16 -> 64+64 live regs -> 32MB spill).
__global__ __launch_bounds__(256, 2) void scan_kernel(const float* __restrict__ q,
                                                      const float* __restrict__ kk,
                                                      const float* __restrict__ vv,
                                                      const unsigned* __restrict__ G,
                                                      float* __restrict__ o,
                                                      int CPG, int NG, float scale) {
    int g = blockIdx.x, h = blockIdx.y, b = blockIdx.z;
    int t = threadIdx.x, l = t & 63, w = t >> 6, hi = l >> 5, lm = l & 31;
    int eb = w;                       // e-slice 0..3
    __shared__ short lq [64 * SQ];    // 17408 B
    __shared__ short lk [64 * SQ];    // 17408 B
    __shared__ short lkT[128 * ST];   // 18432 B
    __shared__ short lvT[128 * ST];   // 18432 B
    __shared__ short lS [64 * ST];    //  9216 B   (total 80896 <= 81920 for 2/CU)

    // h state: 4 d-tiles of e-slice eb, C/D layout, f32 regs
    fx16 h0 = {}, h1 = {}, h2 = {}, h3 = {};
    {
        const unsigned* Gp = G + ((long)(b * HH + h) * NG + g) * (DD * DD / 2);
#define GINIT(hx, db) { const unsigned* p_ = Gp + (long)((db) * 4 + eb) * 512 + l * 8; \
        uint4 u0 = *(const uint4*)p_; uint4 u1 = *(const uint4*)(p_ + 4); \
        UPK(u0.x, hx[0], hx[1]);  UPK(u0.y, hx[2], hx[3]); \
        UPK(u0.z, hx[4], hx[5]);  UPK(u0.w, hx[6], hx[7]); \
        UPK(u1.x, hx[8], hx[9]);  UPK(u1.y, hx[10], hx[11]); \
        UPK(u1.z, hx[12], hx[13]); UPK(u1.w, hx[14], hx[15]); }
        GINIT(h0, 0) GINIT(h1, 1) GINIT(h2, 2) GINIT(h3, 3)
    }

    long hbase = ((long)b * SS) * HD + (long)h * DD;
    int r4 = t >> 2, c4 = t & 3;      // staging: 4 threads per row

    for (int c = 0; c < CPG; ++c) {
        long base = hbase + (long)(g * CPG + c) * CK * HD;
        // ---- stage q,k row-major (unroll capped: <=16 f32 in flight) ----
#pragma unroll 2
        for (int j = 0; j < 8; ++j) {
            long ga = base + (long)r4 * HD + 4 * (c4 + 4 * j);
            float4 qv = *(const float4*)&q[ga];
            float4 kv = *(const float4*)&kk[ga];
            uint2 uq; uq.x = pk2(qv.x * scale, qv.y * scale); uq.y = pk2(qv.z * scale, qv.w * scale);
            *(uint2*)&lq[r4 * SQ + SWZ(4 * (c4 + 4 * j), r4)] = uq;
            uint2 uk; uk.x = pk2(kv.x, kv.y); uk.y = pk2(kv.z, kv.w);
            *(uint2*)&lk[r4 * SQ + SWZ(4 * (c4 + 4 * j), r4)] = uk;
        }
        // ---- stage kT,vT (transposed reads, unroll capped: <=16 f32 in flight) ----
#pragma unroll 4
        for (int i = 0; i < 16; ++i) {
            int it = t + 256 * i;                       // 0..4095
            int e = (it & 31) + 32 * (it >> 10);
            int c2 = (it >> 5) & 31;
            long ga = base + (long)(2 * c2) * HD + e;
            *(unsigned*)&lkT[e * ST + SWZ(2 * c2, e)] = pk2(kk[ga], kk[ga + HD]);
            *(unsigned*)&lvT[e * ST + SWZ(2 * c2, e)] = pk2(vv[ga], vv[ga + HD]);
        }
        __syncthreads();   // B1: stage visible

        __builtin_amdgcn_s_setprio(1);
        // ---- m1 (waves 0-2): one S^T tile each -> masked bf16 -> lS (S row-major) ----
        if (w < 3) {
            int ct = (w == 2) ? 1 : 0;      // c-tile
            int rt = (w == 0) ? 0 : 1;      // r-tile;  (ct,rt) in {(0,0),(0,1),(1,1)}
            fx16 st = {};
#pragma unroll
            for (int ks = 0; ks < 8; ++ks) {
                bh8 A = *(const bh8*)&lk[(32*ct+lm)*SQ + SWZ(16*ks + 8*hi, lm)];
                bh8 B = *(const bh8*)&lq[(32*rt+lm)*SQ + SWZ(16*ks + 8*hi, lm)];
                st = MFMA32(A, B, st);
            }
            bool diag = (ct == rt);
#pragma unroll
            for (int q4 = 0; q4 < 4; ++q4) {
                float m[4];
#pragma unroll
                for (int j = 0; j < 4; ++j) {
                    int cc_ = 8 * q4 + 4 * hi + j;     // local col within tile
                    float x = st[4 * q4 + j];
                    m[j] = (!diag || cc_ <= lm) ? x : 0.f;
                }
                uint2 u; u.x = pk2(m[0], m[1]); u.y = pk2(m[2], m[3]);
                *(uint2*)&lS[(32*rt+lm)*ST + SWZ(32*ct + 8*q4 + 4*hi, lm)] = u;
            }
        }
        __syncthreads();   // B2: S visible

        // shared B-operands from vT (e-slice eb) for m2/m4
        bh8 Bv0 = *(const bh8*)&lvT[(32*eb+lm)*ST + SWZ( 0 + 8*hi, lm)];
        bh8 Bv1 = *(const bh8*)&lvT[(32*eb+lm)*ST + SWZ(16 + 8*hi, lm)];
        bh8 Bv2 = *(const bh8*)&lvT[(32*eb+lm)*ST + SWZ(32 + 8*hi, lm)];
        bh8 Bv3 = *(const bh8*)&lvT[(32*eb+lm)*ST + SWZ(48 + 8*hi, lm)];

        // ---- m2: o = S @ v (A-frags straight from lS) ----
        fx16 oa0 = {}, oa1 = {};
        {
            bh8 A0 = *(const bh8*)&lS[lm*ST      + SWZ( 0 + 8*hi, lm)];
            bh8 A1 = *(const bh8*)&lS[lm*ST      + SWZ(16 + 8*hi, lm)];
            oa0 = MFMA32(A0, Bv0, oa0);
            oa0 = MFMA32(A1, Bv1, oa0);
            bh8 B0 = *(const bh8*)&lS[(32+lm)*ST + SWZ( 0 + 8*hi, lm)];
            bh8 B1 = *(const bh8*)&lS[(32+lm)*ST + SWZ(16 + 8*hi, lm)];
            bh8 B2 = *(const bh8*)&lS[(32+lm)*ST + SWZ(32 + 8*hi, lm)];
            bh8 B3 = *(const bh8*)&lS[(32+lm)*ST + SWZ(48 + 8*hi, lm)];
            oa1 = MFMA32(B0, Bv0, oa1);
            oa1 = MFMA32(B1, Bv1, oa1);
            oa1 = MFMA32(B2, Bv2, oa1);
            oa1 = MFMA32(B3, Bv3, oa1);
        }
        // ---- m3: o += qs @ h (B-frags from reg h; Bh shared across both r-tiles) ----
#define M3STEP(hx, db) { \
        bh8 Bh0; MKFRAG(Bh0, hx, 0); \
        bh8 Aq0 = *(const bh8*)&lq[lm * SQ      + SWZ(16*(2*(db)) + 8*hi, lm)]; \
        bh8 Aq1 = *(const bh8*)&lq[(32+lm) * SQ + SWZ(16*(2*(db)) + 8*hi, lm)]; \
        oa0 = MFMA32(Aq0, Bh0, oa0); oa1 = MFMA32(Aq1, Bh0, oa1); \
        bh8 Bh1; MKFRAG(Bh1, hx, 8); \
        bh8 Aq2 = *(const bh8*)&lq[lm * SQ      + SWZ(16*(2*(db)+1) + 8*hi, lm)]; \
        bh8 Aq3 = *(const bh8*)&lq[(32+lm) * SQ + SWZ(16*(2*(db)+1) + 8*hi, lm)]; \
        oa0 = MFMA32(Aq2, Bh1, oa0); oa1 = MFMA32(Aq3, Bh1, oa1); }
        M3STEP(h0, 0) M3STEP(h1, 1) M3STEP(h2, 2) M3STEP(h3, 3)

        // ---- m4: h += k^T v ----
#define M4STEP(hx, db) { \
        bh8 A0_ = *(const bh8*)&lkT[(32*(db)+lm)*ST + SWZ( 0 + 8*hi, lm)]; hx = MFMA32(A0_, Bv0, hx); \
        bh8 A1_ = *(const bh8*)&lkT[(32*(db)+lm)*ST + SWZ(16 + 8*hi, lm)]; hx = MFMA32(A1_, Bv1, hx); \
        bh8 A2_ = *(const bh8*)&lkT[(32*(db)+lm)*ST + SWZ(32 + 8*hi, lm)]; hx = MFMA32(A2_, Bv2, hx); \
        bh8 A3_ = *(const bh8*)&lkT[(32*(db)+lm)*ST + SWZ(48 + 8*hi, lm)]; hx = MFMA32(A3_, Bv3, hx); }
        M4STEP(h0, 0) M4STEP(h1, 1) M4STEP(h2, 2) M4STEP(h3, 3)
        __builtin_amdgcn_s_setprio(0);

        // ---- o write: oa0 rows 0-31, oa1 rows 32-63, col 32*eb+lm ----
        {
            float* op = o + base;
            int e = 32 * eb + lm;
#pragma unroll
            for (int rg = 0; rg < 16; ++rg) {
                int r = (rg & 3) + 8 * (rg >> 2) + 4 * hi;
                op[(long)r * HD + e]        = oa0[rg];
                op[(long)(32 + r) * HD + e] = oa1[rg];
            }
        }
        __syncthreads();   // B3: all reads done before next stage overwrites
    }
}

extern "C" void kernel_launch(void* const* d_in, const int* in_sizes, int n_in,
                              void* d_out, int out_size, void* d_ws, size_t ws_size,
                              hipStream_t stream) {
    const float* q = (const float*)d_in[0];
    const float* k = (const float*)d_in[1];
    const float* v = (const float*)d_in[2];
    float* o  = (float*)d_out;
    float* hf = o + (long)BB * SS * HH * DD;
    unsigned* G = (unsigned*)d_ws;

    int NG = 16;
    while (NG > 1 && (size_t)BB * HH * NG * DD * DD * 2 > ws_size) NG >>= 1;
    int CPG = NTC / NG;
    float scale = 1.0f / sqrtf((float)DD);

    ksum_kernel<<<dim3(NG, HH, BB), 512, 0, stream>>>(k, v, G, CPG, NG);
    prefix_kernel<<<dim3(256, 1, 1), 256, 0, stream>>>(G, hf, NG);
    scan_kernel<<<dim3(NG, HH, BB), 256, 0, stream>>>(q, k, v, G, o, CPG, NG, scale);
}

// Round 11
// 85.391 us; speedup vs baseline: 2.4224x; 1.0963x over previous
//
#include <hip/hip_runtime.h>
#include <hip/hip_bf16.h>
#include <math.h>

#define BB 2
#define SS 4096
#define HH 16
#define DD 128
#define CK 64
#define NTC 64
#define HD 2048          // H*D row stride (elements)
#define SQ 136           // LDS row stride (shorts), rows of 128 (q, k)
#define ST 72            // LDS row stride (shorts), rows of 64 (kT, vT, S)

typedef __attribute__((ext_vector_type(8))) short bh8;     // 8 bf16
typedef __attribute__((ext_vector_type(16))) float fx16;   // 32x32 accumulator

#define MFMA32(a, b, c) __builtin_amdgcn_mfma_f32_32x32x16_bf16(a, b, c, 0, 0, 0)
// short-offset XOR swizzle: spreads the 8-row bank period across 4 16B slots
#define SWZ(off, row) ((off) ^ (8 * (((row) >> 3) & 3)))

__device__ inline unsigned pk2(float a, float b) {   // 2xf32 -> packed bf16 (RNE, hw cvt)
    union { __hip_bfloat162 h2; unsigned u; } r;
    r.h2.x = __float2bfloat16(a);
    r.h2.y = __float2bfloat16(b);
    return r.u;
}
// packed bf16 -> 2xf32 (exact); macro so it can assign to vector elements
#define UPK(u, x, y) { x = __uint_as_float((unsigned)(u) << 16); y = __uint_as_float((unsigned)(u) & 0xFFFF0000u); }

// exchange: x' = {x.lo, y.lo(partner)}, y' = {x.hi(partner), y.hi}
#define SWAP32(x, y) asm("v_permlane32_swap_b32 %0, %1" : "+v"(x), "+v"(y))

// Build an MFMA A/B fragment (8 consecutive k per hi-half) from 16 C/D-layout
// f32 regs: pack pairs, one permlane swap fixes the hi-half mismatch.
#define MKFRAG(dst, cc, O) { \
    unsigned a0_ = pk2(cc[(O)+0], cc[(O)+1]), a1_ = pk2(cc[(O)+2], cc[(O)+3]); \
    unsigned a2_ = pk2(cc[(O)+4], cc[(O)+5]), a3_ = pk2(cc[(O)+6], cc[(O)+7]); \
    SWAP32(a0_, a2_); SWAP32(a1_, a3_); \
    union { unsigned u[4]; bh8 v; } r_; \
    r_.u[0] = a0_; r_.u[1] = a1_; r_.u[2] = a2_; r_.u[3] = a3_; \
    dst = r_.v; }

// Write one 2x4 transposed micro-tile (rows a=row c, b=row c+1, cols e0..e0+3)
#define TWRITE(buf, e0, c2w, fa, fb) { \
    *(unsigned*)&buf[((e0)+0) * ST + SWZ(2*(c2w), (e0)+0)] = pk2(fa.x, fb.x); \
    *(unsigned*)&buf[((e0)+1) * ST + SWZ(2*(c2w), (e0)+1)] = pk2(fa.y, fb.y); \
    *(unsigned*)&buf[((e0)+2) * ST + SWZ(2*(c2w), (e0)+2)] = pk2(fa.z, fb.z); \
    *(unsigned*)&buf[((e0)+3) * ST + SWZ(2*(c2w), (e0)+3)] = pk2(fa.w, fb.w); }

// ---------------- Phase 1: per-group K^T V sums (dbuf, reg-h, bf16 frag G) ----------
// float4 transposed staging: 8 VMEM inst/thread/chunk (was 32 scalar -> issue-bound).
__global__ __launch_bounds__(512, 2) void ksum_kernel(const float* __restrict__ k,
                                                      const float* __restrict__ v,
                                                      unsigned* __restrict__ G,
                                                      int CPG, int NG) {
    int g = blockIdx.x, h = blockIdx.y, b = blockIdx.z;
    int t = threadIdx.x, l = t & 63, w = t >> 6, hi = l >> 5, lm = l & 31;
    int dbp = 2 * (w >> 2), eb = w & 3;   // wave owns h tiles (dbp,eb),(dbp+1,eb)
    __shared__ short lkT[2][128 * ST];
    __shared__ short lvT[2][128 * ST];
    fx16 h0 = {}, h1 = {};
    long hbase = ((long)b * SS) * HD + (long)h * DD;
    float4 kA[2], kB[2], vA[2], vB[2];   // 2 micro-tiles (32 regs held)

#define KLOAD(cc) { long base_ = hbase + (long)(g * CPG + (cc)) * CK * HD; \
    _Pragma("unroll") for (int j = 0; j < 2; ++j) { int fl_ = t + 512 * j; \
        int e4 = fl_ & 31, c2 = (fl_ >> 5) & 31; \
        long ga = base_ + (long)(2 * c2) * HD + 4 * e4; \
        kA[j] = *(const float4*)&k[ga]; kB[j] = *(const float4*)&k[ga + HD]; \
        vA[j] = *(const float4*)&v[ga]; vB[j] = *(const float4*)&v[ga + HD]; } }

#define KSTAGE(pn) { \
    _Pragma("unroll") for (int j = 0; j < 2; ++j) { int fl_ = t + 512 * j; \
        int e4 = fl_ & 31, c2 = (fl_ >> 5) & 31; int e0 = 4 * e4; \
        TWRITE(lkT[pn], e0, c2, kA[j], kB[j]); \
        TWRITE(lvT[pn], e0, c2, vA[j], vB[j]); } }

    KLOAD(0); KSTAGE(0); if (CPG > 1) KLOAD(1);
    __syncthreads();
    int p = 0;
    for (int c = 0; c < CPG; ++c) {
        if (c + 1 < CPG) KSTAGE(p ^ 1);
        if (c + 2 < CPG) KLOAD(c + 2);
        bh8 Bv0 = *(const bh8*)&lvT[p][(32*eb+lm)*ST + SWZ( 0 + 8*hi, lm)];
        bh8 Bv1 = *(const bh8*)&lvT[p][(32*eb+lm)*ST + SWZ(16 + 8*hi, lm)];
        bh8 Bv2 = *(const bh8*)&lvT[p][(32*eb+lm)*ST + SWZ(32 + 8*hi, lm)];
        bh8 Bv3 = *(const bh8*)&lvT[p][(32*eb+lm)*ST + SWZ(48 + 8*hi, lm)];
        __builtin_amdgcn_s_setprio(1);
#define KM4(hx, db) { \
        bh8 A0_ = *(const bh8*)&lkT[p][(32*(db)+lm)*ST + SWZ( 0 + 8*hi, lm)]; hx = MFMA32(A0_, Bv0, hx); \
        bh8 A1_ = *(const bh8*)&lkT[p][(32*(db)+lm)*ST + SWZ(16 + 8*hi, lm)]; hx = MFMA32(A1_, Bv1, hx); \
        bh8 A2_ = *(const bh8*)&lkT[p][(32*(db)+lm)*ST + SWZ(32 + 8*hi, lm)]; hx = MFMA32(A2_, Bv2, hx); \
        bh8 A3_ = *(const bh8*)&lkT[p][(32*(db)+lm)*ST + SWZ(48 + 8*hi, lm)]; hx = MFMA32(A3_, Bv3, hx); }
        KM4(h0, dbp) KM4(h1, dbp + 1)
        __builtin_amdgcn_s_setprio(0);
        __syncthreads();
        p ^= 1;
    }
    // bf16 fragment-ordered G: tile (db,eb) at (db*4+eb)*512 u32 + lane*8
    unsigned* Gp = G + ((long)(b * HH + h) * NG + g) * (DD * DD / 2);
    long t0 = (long)(dbp * 4 + eb) * 512 + l * 8;
    long t1 = (long)((dbp + 1) * 4 + eb) * 512 + l * 8;
    uint4 u;
    u.x = pk2(h0[0],h0[1]);  u.y = pk2(h0[2],h0[3]);  u.z = pk2(h0[4],h0[5]);  u.w = pk2(h0[6],h0[7]);
    *(uint4*)(Gp + t0) = u;
    u.x = pk2(h0[8],h0[9]);  u.y = pk2(h0[10],h0[11]); u.z = pk2(h0[12],h0[13]); u.w = pk2(h0[14],h0[15]);
    *(uint4*)(Gp + t0 + 4) = u;
    u.x = pk2(h1[0],h1[1]);  u.y = pk2(h1[2],h1[3]);  u.z = pk2(h1[4],h1[5]);  u.w = pk2(h1[6],h1[7]);
    *(uint4*)(Gp + t1) = u;
    u.x = pk2(h1[8],h1[9]);  u.y = pk2(h1[10],h1[11]); u.z = pk2(h1[12],h1[13]); u.w = pk2(h1[14],h1[15]);
    *(uint4*)(Gp + t1 + 4) = u;
}

// ---------------- Phase 2: exclusive prefix over groups (in-place, bf16 frags) -------
__global__ __launch_bounds__(256) void prefix_kernel(unsigned* __restrict__ G,
                                                     float* __restrict__ hf,
                                                     int NG) {
    int tid = blockIdx.x * 256 + threadIdx.x;     // 65536 threads
    int bh = tid >> 11;
    int fl = (tid & 2047) * 8;                    // frag float base within bh
    unsigned* Gb = G + (long)bh * NG * (DD * DD / 2) + fl / 2;
    float a[8] = {0.f, 0.f, 0.f, 0.f, 0.f, 0.f, 0.f, 0.f};
    uint4 nxt = *(uint4*)Gb;
    for (int g = 0; g < NG; ++g) {
        uint4 cur = nxt;
        if (g + 1 < NG) nxt = *(uint4*)(Gb + (long)(g + 1) * (DD * DD / 2));
        uint4 st;
        st.x = pk2(a[0], a[1]); st.y = pk2(a[2], a[3]);
        st.z = pk2(a[4], a[5]); st.w = pk2(a[6], a[7]);
        *(uint4*)(Gb + (long)g * (DD * DD / 2)) = st;
        float x, y;
        UPK(cur.x, x, y); a[0] += x; a[1] += y;
        UPK(cur.y, x, y); a[2] += x; a[3] += y;
        UPK(cur.z, x, y); a[4] += x; a[5] += y;
        UPK(cur.w, x, y); a[6] += x; a[7] += y;
    }
    // scatter running total into semantic final_state hf[d][e] (f32)
    float* hb = hf + (long)bh * (DD * DD);
    int tile = fl >> 10, li = (fl >> 4) & 63;
#pragma unroll
    for (int j = 0; j < 8; ++j) {
        int rg = (fl & 15) + j;
        int d = 32 * (tile >> 2) + (rg & 3) + 8 * (rg >> 2) + 4 * (li >> 5);
        int e = 32 * (tile & 3) + (li & 31);
        hb[d * DD + e] = a[j];
    }
}

// ---------------- Phase 3: scan, 256-thr, S via LDS, float4 micro-tile staging -------
// Wave w owns e-slice w of h (64 acc regs) and o (64x32). Staging: 32 float4 VMEM
// per thread per chunk (was 16 f4 + 64 scalar); unroll keeps <=32 f32 in flight.
__global__ __launch_bounds__(256, 2) void scan_kernel(const float* __restrict__ q,
                                                      const float* __restrict__ kk,
                                                      const float* __restrict__ vv,
                                                      const unsigned* __restrict__ G,
                                                      float* __restrict__ o,
                                                      int CPG, int NG, float scale) {
    int g = blockIdx.x, h = blockIdx.y, b = blockIdx.z;
    int t = threadIdx.x, l = t & 63, w = t >> 6, hi = l >> 5, lm = l & 31;
    int eb = w;                       // e-slice 0..3
    __shared__ short lq [64 * SQ];    // 17408 B
    __shared__ short lk [64 * SQ];    // 17408 B
    __shared__ short lkT[128 * ST];   // 18432 B
    __shared__ short lvT[128 * ST];   // 18432 B
    __shared__ short lS [64 * ST];    //  9216 B   (total 80896 <= 81920 for 2/CU)

    // h state: 4 d-tiles of e-slice eb, C/D layout, f32 regs
    fx16 h0 = {}, h1 = {}, h2 = {}, h3 = {};
    {
        const unsigned* Gp = G + ((long)(b * HH + h) * NG + g) * (DD * DD / 2);
#define GINIT(hx, db) { const unsigned* p_ = Gp + (long)((db) * 4 + eb) * 512 + l * 8; \
        uint4 u0 = *(const uint4*)p_; uint4 u1 = *(const uint4*)(p_ + 4); \
        UPK(u0.x, hx[0], hx[1]);  UPK(u0.y, hx[2], hx[3]); \
        UPK(u0.z, hx[4], hx[5]);  UPK(u0.w, hx[6], hx[7]); \
        UPK(u1.x, hx[8], hx[9]);  UPK(u1.y, hx[10], hx[11]); \
        UPK(u1.z, hx[12], hx[13]); UPK(u1.w, hx[14], hx[15]); }
        GINIT(h0, 0) GINIT(h1, 1) GINIT(h2, 2) GINIT(h3, 3)
    }

    long hbase = ((long)b * SS) * HD + (long)h * DD;
    int r4 = t >> 2, c4 = t & 3;      // q/k staging: 4 threads per row

    for (int c = 0; c < CPG; ++c) {
        long base = hbase + (long)(g * CPG + c) * CK * HD;
        // ---- stage q,k row-major (unroll 4: 8 float4 in flight) ----
#pragma unroll 4
        for (int j = 0; j < 8; ++j) {
            long ga = base + (long)r4 * HD + 4 * (c4 + 4 * j);
            float4 qv = *(const float4*)&q[ga];
            float4 kv = *(const float4*)&kk[ga];
            uint2 uq; uq.x = pk2(qv.x * scale, qv.y * scale); uq.y = pk2(qv.z * scale, qv.w * scale);
            *(uint2*)&lq[r4 * SQ + SWZ(4 * (c4 + 4 * j), r4)] = uq;
            uint2 uk; uk.x = pk2(kv.x, kv.y); uk.y = pk2(kv.z, kv.w);
            *(uint2*)&lk[r4 * SQ + SWZ(4 * (c4 + 4 * j), r4)] = uk;
        }
        // ---- stage kT,vT via 2x4 float4 micro-tiles (unroll 2: 8 f4 in flight) ----
#pragma unroll 2
        for (int i = 0; i < 4; ++i) {
            int fl_ = t + 256 * i;                      // micro-tile id 0..1023
            int e4 = fl_ & 31, c2 = (fl_ >> 5) & 31;
            long ga = base + (long)(2 * c2) * HD + 4 * e4;
            float4 ka = *(const float4*)&kk[ga];
            float4 kb = *(const float4*)&kk[ga + HD];
            float4 va = *(const float4*)&vv[ga];
            float4 vb = *(const float4*)&vv[ga + HD];
            int e0 = 4 * e4;
            TWRITE(lkT, e0, c2, ka, kb);
            TWRITE(lvT, e0, c2, va, vb);
        }
        __syncthreads();   // B1: stage visible

        __builtin_amdgcn_s_setprio(1);
        // ---- m1 (waves 0-2): one S^T tile each -> masked bf16 -> lS (S row-major) ----
        if (w < 3) {
            int ct = (w == 2) ? 1 : 0;      // c-tile
            int rt = (w == 0) ? 0 : 1;      // r-tile;  (ct,rt) in {(0,0),(0,1),(1,1)}
            fx16 st = {};
#pragma unroll
            for (int ks = 0; ks < 8; ++ks) {
                bh8 A = *(const bh8*)&lk[(32*ct+lm)*SQ + SWZ(16*ks + 8*hi, lm)];
                bh8 B = *(const bh8*)&lq[(32*rt+lm)*SQ + SWZ(16*ks + 8*hi, lm)];
                st = MFMA32(A, B, st);
            }
            bool diag = (ct == rt);
#pragma unroll
            for (int q4 = 0; q4 < 4; ++q4) {
                float m[4];
#pragma unroll
                for (int j = 0; j < 4; ++j) {
                    int cc_ = 8 * q4 + 4 * hi + j;     // local col within tile
                    float x = st[4 * q4 + j];
                    m[j] = (!diag || cc_ <= lm) ? x : 0.f;
                }
                uint2 u; u.x = pk2(m[0], m[1]); u.y = pk2(m[2], m[3]);
                *(uint2*)&lS[(32*rt+lm)*ST + SWZ(32*ct + 8*q4 + 4*hi, lm)] = u;
            }
        }
        __syncthreads();   // B2: S visible

        // shared B-operands from vT (e-slice eb) for m2/m4
        bh8 Bv0 = *(const bh8*)&lvT[(32*eb+lm)*ST + SWZ( 0 + 8*hi, lm)];
        bh8 Bv1 = *(const bh8*)&lvT[(32*eb+lm)*ST + SWZ(16 + 8*hi, lm)];
        bh8 Bv2 = *(const bh8*)&lvT[(32*eb+lm)*ST + SWZ(32 + 8*hi, lm)];
        bh8 Bv3 = *(const bh8*)&lvT[(32*eb+lm)*ST + SWZ(48 + 8*hi, lm)];

        // ---- m2: o = S @ v (A-frags straight from lS) ----
        fx16 oa0 = {}, oa1 = {};
        {
            bh8 A0 = *(const bh8*)&lS[lm*ST      + SWZ( 0 + 8*hi, lm)];
            bh8 A1 = *(const bh8*)&lS[lm*ST      + SWZ(16 + 8*hi, lm)];
            oa0 = MFMA32(A0, Bv0, oa0);
            oa0 = MFMA32(A1, Bv1, oa0);
            bh8 B0 = *(const bh8*)&lS[(32+lm)*ST + SWZ( 0 + 8*hi, lm)];
            bh8 B1 = *(const bh8*)&lS[(32+lm)*ST + SWZ(16 + 8*hi, lm)];
            bh8 B2 = *(const bh8*)&lS[(32+lm)*ST + SWZ(32 + 8*hi, lm)];
            bh8 B3 = *(const bh8*)&lS[(32+lm)*ST + SWZ(48 + 8*hi, lm)];
            oa1 = MFMA32(B0, Bv0, oa1);
            oa1 = MFMA32(B1, Bv1, oa1);
            oa1 = MFMA32(B2, Bv2, oa1);
            oa1 = MFMA32(B3, Bv3, oa1);
        }
        // ---- m3: o += qs @ h (B-frags from reg h; Bh shared across both r-tiles) ----
#define M3STEP(hx, db) { \
        bh8 Bh0; MKFRAG(Bh0, hx, 0); \
        bh8 Aq0 = *(const bh8*)&lq[lm * SQ      + SWZ(16*(2*(db)) + 8*hi, lm)]; \
        bh8 Aq1 = *(const bh8*)&lq[(32+lm) * SQ + SWZ(16*(2*(db)) + 8*hi, lm)]; \
        oa0 = MFMA32(Aq0, Bh0, oa0); oa1 = MFMA32(Aq1, Bh0, oa1); \
        bh8 Bh1; MKFRAG(Bh1, hx, 8); \
        bh8 Aq2 = *(const bh8*)&lq[lm * SQ      + SWZ(16*(2*(db)+1) + 8*hi, lm)]; \
        bh8 Aq3 = *(const bh8*)&lq[(32+lm) * SQ + SWZ(16*(2*(db)+1) + 8*hi, lm)]; \
        oa0 = MFMA32(Aq2, Bh1, oa0); oa1 = MFMA32(Aq3, Bh1, oa1); }
        M3STEP(h0, 0) M3STEP(h1, 1) M3STEP(h2, 2) M3STEP(h3, 3)

        // ---- m4: h += k^T v ----
#define M4STEP(hx, db) { \
        bh8 A0_ = *(const bh8*)&lkT[(32*(db)+lm)*ST + SWZ( 0 + 8*hi, lm)]; hx = MFMA32(A0_, Bv0, hx); \
        bh8 A1_ = *(const bh8*)&lkT[(32*(db)+lm)*ST + SWZ(16 + 8*hi, lm)]; hx = MFMA32(A1_, Bv1, hx); \
        bh8 A2_ = *(const bh8*)&lkT[(32*(db)+lm)*ST + SWZ(32 + 8*hi, lm)]; hx = MFMA32(A2_, Bv2, hx); \
        bh8 A3_ = *(const bh8*)&lkT[(32*(db)+lm)*ST + SWZ(48 + 8*hi, lm)]; hx = MFMA32(A3_, Bv3, hx); }
        M4STEP(h0, 0) M4STEP(h1, 1) M4STEP(h2, 2) M4STEP(h3, 3)
        __builtin_amdgcn_s_setprio(0);

        // ---- o write: oa0 rows 0-31, oa1 rows 32-63, col 32*eb+lm ----
        {
            float* op = o + base;
            int e = 32 * eb + lm;
#pragma unroll
            for (int rg = 0; rg < 16; ++rg) {
                int r = (rg & 3) + 8 * (rg >> 2) + 4 * hi;
                op[(long)r * HD + e]        = oa0[rg];
                op[(long)(32 + r) * HD + e] = oa1[rg];
            }
        }
        __syncthreads();   // B3: all reads done before next stage overwrites
    }
}

extern "C" void kernel_launch(void* const* d_in, const int* in_sizes, int n_in,
                              void* d_out, int out_size, void* d_ws, size_t ws_size,
                              hipStream_t stream) {
    const float* q = (const float*)d_in[0];
    const float* k = (const float*)d_in[1];
    const float* v = (const float*)d_in[2];
    float* o  = (float*)d_out;
    float* hf = o + (long)BB * SS * HH * DD;
    unsigned* G = (unsigned*)d_ws;

    int NG = 16;
    while (NG > 1 && (size_t)BB * HH * NG * DD * DD * 2 > ws_size) NG >>= 1;
    int CPG = NTC / NG;
    float scale = 1.0f / sqrtf((float)DD);

    ksum_kernel<<<dim3(NG, HH, BB), 512, 0, stream>>>(k, v, G, CPG, NG);
    prefix_kernel<<<dim3(256, 1, 1), 256, 0, stream>>>(G, hf, NG);
    scan_kernel<<<dim3(NG, HH, BB), 256, 0, stream>>>(q, k, v, G, o, CPG, NG, scale);
}